// Round 5
// baseline (1549.799 us; speedup 1.0000x reference)
//
#include <hip/hip_runtime.h>
#include <hip/hip_cooperative_groups.h>
#include <cstdint>
#include <cstddef>

#define NTOK 8192
#define NE 512
#define EDIM 256
#define NEXPALL 11
#define NITER 100

namespace cg = cooperative_groups;

static __device__ __forceinline__ double wredsum(double x) {
  for (int o = 32; o > 0; o >>= 1) x += __shfl_down(x, o, 64);
  return x;
}

static constexpr double S32 = 2.3283064365386963e-10; // 2^-32
static constexpr double Q32 = 4294967296.0;           // 2^32

// ---------------- init (EVERYTHING read-before-write in d_ws, incl. dmaxA/dminA:
// R3/R4 bug was poisoned 0xAA dmaxA winning the unsigned atomicMax -> negative amp) ----
__global__ void k_init(unsigned* colmin, double* r, double* uprev, int* ctrl, double* sums,
                       unsigned* dmaxA, unsigned* dminA) {
  int i = blockIdx.x * 256 + threadIdx.x;
  if (i < NEXPALL * NTOK) colmin[i] = 0x7F800000u; // +inf f32
  if (i < NEXPALL * NE) { r[i] = 0.0; uprev[i] = 0.0; }
  if (i < 16) ctrl[i] = 0; // [0]=nfrozen [1]=snap [2..12]=frozen
  if (i < 2) sums[i] = 0.0;
  if (i < NEXPALL) { dmaxA[i] = 0u; dminA[i] = 0x7F800000u; }
}

// ---------------- numpy-pairwise sum of squares (f32, bit-exact tree) ----------------
__global__ __launch_bounds__(256) void k_npsq(const float* __restrict__ p, float* __restrict__ o, int rows) {
  int r = blockIdx.x * 16 + (threadIdx.x >> 4);
  int l = threadIdx.x & 15;
  if (r >= rows) return;
  const float* a = p + (size_t)r * EDIM;
  int leaf = l >> 3;
  int j = l & 7;
  const float* base = a + leaf * 128 + j;
  float acc = __fmul_rn(base[0], base[0]);
#pragma unroll
  for (int i = 8; i < 128; i += 8) {
    float v = base[i];
    acc = __fadd_rn(acc, __fmul_rn(v, v));
  }
  acc = __fadd_rn(acc, __shfl_xor(acc, 1, 64));
  acc = __fadd_rn(acc, __shfl_xor(acc, 2, 64));
  acc = __fadd_rn(acc, __shfl_xor(acc, 4, 64));
  float other = __shfl_xor(acc, 8, 64);
  float tot = (leaf == 0) ? __fadd_rn(acc, other) : __fadd_rn(other, acc);
  if (l == 0) o[r] = tot;
}

// ---------------- K1: f32 GEMM 128x128 tile, 8x8/thread, K-transposed LDS ----------------
// per-element m is ONE ascending-k fmaf chain -> bit-identical to BLAS kernel semantics
__global__ __launch_bounds__(256) void k_gemm_d(const float* __restrict__ x, const float* __restrict__ emb,
                                                const float* __restrict__ sx, const float* __restrict__ sw,
                                                float* __restrict__ bigF,
                                                unsigned* __restrict__ colminA,
                                                unsigned* __restrict__ dmaxA,
                                                unsigned* __restrict__ dminA) {
  int bx = blockIdx.x, by = blockIdx.y, e = blockIdx.z;
  int tid = threadIdx.x;
  int tx = tid & 15, ty = tid >> 4;
  int b0 = bx * 128, k0 = by * 128;
  __shared__ float As[16][128]; // [k][m]
  __shared__ float Bs[16][128]; // [k][n]
  __shared__ float sxs[128];
  __shared__ float sws[128];
  __shared__ unsigned colm[128];
  __shared__ float wrx[4], wrn[4];
  if (tid < 128) { sxs[tid] = sx[b0 + tid]; colm[tid] = 0x7F800000u; }
  else { sws[tid - 128] = sw[e * NE + k0 + tid - 128]; }
  float acc[8][8] = {};
  const float* xb = x + (size_t)b0 * EDIM;
  const float* wb = emb + ((size_t)e * NE + k0) * EDIM;
  int lr = tid >> 1, lco = (tid & 1) * 8;
  for (int kc = 0; kc < EDIM; kc += 16) {
    float4 x0 = *(const float4*)(xb + (size_t)lr * EDIM + kc + lco);
    float4 x1 = *(const float4*)(xb + (size_t)lr * EDIM + kc + lco + 4);
    float4 e0 = *(const float4*)(wb + (size_t)lr * EDIM + kc + lco);
    float4 e1 = *(const float4*)(wb + (size_t)lr * EDIM + kc + lco + 4);
    __syncthreads();
    As[lco + 0][lr] = x0.x; As[lco + 1][lr] = x0.y; As[lco + 2][lr] = x0.z; As[lco + 3][lr] = x0.w;
    As[lco + 4][lr] = x1.x; As[lco + 5][lr] = x1.y; As[lco + 6][lr] = x1.z; As[lco + 7][lr] = x1.w;
    Bs[lco + 0][lr] = e0.x; Bs[lco + 1][lr] = e0.y; Bs[lco + 2][lr] = e0.z; Bs[lco + 3][lr] = e0.w;
    Bs[lco + 4][lr] = e1.x; Bs[lco + 5][lr] = e1.y; Bs[lco + 6][lr] = e1.z; Bs[lco + 7][lr] = e1.w;
    __syncthreads();
#pragma unroll
    for (int kk = 0; kk < 16; ++kk) {
      float a[8], b[8];
      *(float4*)&a[0] = *(const float4*)&As[kk][ty * 4];
      *(float4*)&a[4] = *(const float4*)&As[kk][64 + ty * 4];
      *(float4*)&b[0] = *(const float4*)&Bs[kk][tx * 4];
      *(float4*)&b[4] = *(const float4*)&Bs[kk][64 + tx * 4];
#pragma unroll
      for (int i = 0; i < 8; ++i)
#pragma unroll
        for (int j = 0; j < 8; ++j)
          acc[i][j] = fmaf(a[i], b[j], acc[i][j]);
    }
  }
  float dmx = -3.0e38f, dmn = 3.0e38f;
#pragma unroll
  for (int i = 0; i < 8; ++i) {
    int m = (i < 4) ? (ty * 4 + i) : (64 + ty * 4 + i - 4);
    float cmin = 3.0e38f;
#pragma unroll
    for (int j = 0; j < 8; ++j) {
      int n = (j < 4) ? (tx * 4 + j) : (64 + tx * 4 + j - 4);
      float dv = __fsub_rn(__fadd_rn(sxs[m], sws[n]), __fmul_rn(2.0f, acc[i][j]));
      acc[i][j] = dv;
      dmx = fmaxf(dmx, dv); dmn = fminf(dmn, dv);
      cmin = fminf(cmin, dv);
    }
    atomicMin(&colm[m], __float_as_uint(cmin)); // d>0 -> uint order == float order
  }
  for (int o = 32; o > 0; o >>= 1) {
    dmx = fmaxf(dmx, __shfl_down(dmx, o, 64));
    dmn = fminf(dmn, __shfl_down(dmn, o, 64));
  }
  int wv = tid >> 6, ln = tid & 63;
  if (ln == 0) { wrx[wv] = dmx; wrn[wv] = dmn; }
  __syncthreads();
  if (tid == 0) {
    atomicMax(dmaxA + e, __float_as_uint(fmaxf(fmaxf(wrx[0], wrx[1]), fmaxf(wrx[2], wrx[3]))));
    atomicMin(dminA + e, __float_as_uint(fminf(fminf(wrn[0], wrn[1]), fminf(wrn[2], wrn[3]))));
  }
  if (tid < 128) atomicMin(colminA + (size_t)e * NTOK + b0 + tid, colm[tid]);
#pragma unroll
  for (int j = 0; j < 8; ++j) {
    int n = (j < 4) ? (tx * 4 + j) : (64 + tx * 4 + j - 4);
    float* op = bigF + ((size_t)e * NE + k0 + n) * NTOK + b0;
    float4 v0 = make_float4(acc[0][j], acc[1][j], acc[2][j], acc[3][j]);
    float4 v1 = make_float4(acc[4][j], acc[5][j], acc[6][j], acc[7][j]);
    *(float4*)(op + ty * 4) = v0;
    *(float4*)(op + 64 + ty * 4) = v1;
  }
}

// ---------------- K2: per-token colmax logit + v0 ----------------
__global__ __launch_bounds__(256) void k_prep(const unsigned* __restrict__ colminA,
                                              const unsigned* __restrict__ dmaxA,
                                              const unsigned* __restrict__ dminA,
                                              double* __restrict__ cml, double* __restrict__ v) {
  int e = blockIdx.y;
  int b = blockIdx.x * 256 + threadIdx.x;
  float mx = __uint_as_float(dmaxA[e]);
  float mn = __uint_as_float(dminA[e]);
  float mid = __fmul_rn(__fadd_rn(mx, mn), 0.5f);
  float amp = __fadd_rn(__fsub_rn(mx, mid), 1e-5f);
  float cminf = __uint_as_float(colminA[(size_t)e * NTOK + b]);
  float dn = __fdiv_rn(__fsub_rn(cminf, mid), amp);
  double l = (-(double)dn) / 0.01;
  cml[(size_t)e * NTOK + b] = l;
  v[(size_t)e * NTOK + b] = exp(l);
}

// ---------------- K3: build B (u32 fixed point of 1-B, in place) + r0 ----------------
__global__ __launch_bounds__(256) void k_build(float* __restrict__ bigF,
                                               const unsigned* __restrict__ dmaxA,
                                               const unsigned* __restrict__ dminA,
                                               const double* __restrict__ cml, const double* __restrict__ v0,
                                               double* __restrict__ r0) {
  int bx = blockIdx.x, k = blockIdx.y, e = blockIdx.z;
  int tid = threadIdx.x;
  float mx = __uint_as_float(dmaxA[e]);
  float mn = __uint_as_float(dminA[e]);
  float mid = __fmul_rn(__fadd_rn(mx, mn), 0.5f);
  float amp = __fadd_rn(__fsub_rn(mx, mid), 1e-5f);
  size_t rb = ((size_t)e * NE + k) * NTOK;
  int cb = bx * 2048 + tid * 8;
  float4 fa = *(const float4*)(bigF + rb + cb);
  float4 fb = *(const float4*)(bigF + rb + cb + 4);
  float din[8] = {fa.x, fa.y, fa.z, fa.w, fb.x, fb.y, fb.z, fb.w};
  unsigned qo[8];
  double racc = 0.0;
#pragma unroll
  for (int j = 0; j < 8; ++j) {
    int b = cb + j;
    float dn = __fdiv_rn(__fsub_rn(din[j], mid), amp);
    double l = (-(double)dn) / 0.01;
    double t = l - cml[(size_t)e * NTOK + b]; // <= 0
    double Bv = exp(t);
    double qd = (1.0 - Bv) * Q32;
    qd = fmin(fmax(qd, 0.0), 4294967295.0);
    unsigned q = (unsigned)llrint(qd);
    qo[j] = q;
    double Bq = fma(-(double)q, S32, 1.0);
    racc = fma(Bq, v0[(size_t)e * NTOK + b], racc);
  }
  uint4 oa = make_uint4(qo[0], qo[1], qo[2], qo[3]);
  uint4 ob2 = make_uint4(qo[4], qo[5], qo[6], qo[7]);
  *(uint4*)((unsigned*)bigF + rb + cb) = oa;
  *(uint4*)((unsigned*)bigF + rb + cb + 4) = ob2;
  racc = wredsum(racc);
  __shared__ double pr[4];
  int wv = tid >> 6, ln = tid & 63;
  if (ln == 0) pr[wv] = racc;
  __syncthreads();
  if (tid == 0) atomicAdd(&r0[e * NE + k], (pr[0] + pr[1]) + (pr[2] + pr[3]));
}

// ---------------- K4: fused cooperative sinkhorn loop + final argmax ----------------
// control flags written only in the inter-sync window, read only at top-of-iter via
// tid0->LDS broadcast; every write window separated from every read window by grid.sync.
__global__ __launch_bounds__(256, 2) void k_sink(const unsigned* __restrict__ bigU,
                                                 double* __restrict__ r,
                                                 double* __restrict__ v,
                                                 double* __restrict__ uprev,
                                                 int* __restrict__ nfrozen,
                                                 int* __restrict__ snap,
                                                 int* __restrict__ frozen,
                                                 int* __restrict__ idxs) {
  cg::grid_group grid = cg::this_grid();
  int blk = blockIdx.x;
  int e = blk >> 5;
  int chunk = blk & 31;
  int tid = threadIdx.x;
  int wv = tid >> 6, ln = tid & 63;
  size_t ebase = (size_t)e * (size_t)NE * NTOK;
  __shared__ double us[NE];
  __shared__ double pr[16][4];
  __shared__ int sokf, s_snap, s_fro;

  for (int t = 1; t <= NITER; ++t) {
    if (tid == 0) {
      s_snap = *(volatile int*)snap;
      s_fro = ((volatile int*)frozen)[e];
    }
    __syncthreads();
    if (s_snap == NEXPALL) break; // uniform: snap stable in this window
    bool fro = (s_fro != 0);      // uniform within block AND across the expert's blocks
    if (!fro) {
      int k2 = tid * 2;
      double u0 = 1.0 / (512.0 * r[e * NE + k2]);
      double u1 = 1.0 / (512.0 * r[e * NE + k2 + 1]);
      us[k2] = u0; us[k2 + 1] = u1;
      if (tid == 0) sokf = 1;
      __syncthreads();
      if (chunk == 0) {
        double p0 = uprev[e * NE + k2], p1 = uprev[e * NE + k2 + 1];
        bool ok = (fabs(u0 - p0) <= 1e-13 * fabs(u0)) && (fabs(u1 - p1) <= 1e-13 * fabs(u1));
        if (!ok) sokf = 0;
        uprev[e * NE + k2] = u0; uprev[e * NE + k2 + 1] = u1;
      }
      int col = chunk * 256 + tid;
      const unsigned* cp = bigU + ebase + col;
      double c0 = 0, c1 = 0, c2 = 0, c3 = 0;
#pragma unroll 2
      for (int k = 0; k < NE; k += 4) {
        unsigned q0 = cp[(size_t)(k + 0) * NTOK];
        unsigned q1 = cp[(size_t)(k + 1) * NTOK];
        unsigned q2 = cp[(size_t)(k + 2) * NTOK];
        unsigned q3 = cp[(size_t)(k + 3) * NTOK];
        c0 = fma(us[k + 0], fma(-(double)q0, S32, 1.0), c0);
        c1 = fma(us[k + 1], fma(-(double)q1, S32, 1.0), c1);
        c2 = fma(us[k + 2], fma(-(double)q2, S32, 1.0), c2);
        c3 = fma(us[k + 3], fma(-(double)q3, S32, 1.0), c3);
      }
      v[(size_t)e * NTOK + col] = 1.0 / (8192.0 * ((c0 + c1) + (c2 + c3)));
    }
    grid.sync();
    // ---- control window: the ONLY place frozen/nfrozen/snap are written ----
    if (chunk == 0 && !fro && tid == 0 && sokf) {
      ((volatile int*)frozen)[e] = 1;
      atomicAdd(nfrozen, 1);
    }
    if (blk == 0 && tid == 0) *(volatile int*)snap = *(volatile int*)nfrozen;
    if (t < NITER && !fro) {
      double vr[32];
#pragma unroll
      for (int j = 0; j < 8; ++j) {
        double4 vq = *(const double4*)(v + (size_t)e * NTOK + j * 1024 + tid * 4);
        vr[4 * j + 0] = vq.x; vr[4 * j + 1] = vq.y; vr[4 * j + 2] = vq.z; vr[4 * j + 3] = vq.w;
      }
#pragma unroll 1
      for (int rr = 0; rr < 16; ++rr) {
        const unsigned* rp = bigU + ebase + (size_t)(chunk * 16 + rr) * NTOK + tid * 4;
        double a = 0;
#pragma unroll
        for (int j = 0; j < 8; ++j) {
          uint4 q = *(const uint4*)(rp + j * 1024);
          a = fma(fma(-(double)q.x, S32, 1.0), vr[4 * j + 0], a);
          a = fma(fma(-(double)q.y, S32, 1.0), vr[4 * j + 1], a);
          a = fma(fma(-(double)q.z, S32, 1.0), vr[4 * j + 2], a);
          a = fma(fma(-(double)q.w, S32, 1.0), vr[4 * j + 3], a);
        }
        a = wredsum(a);
        if (ln == 0) pr[rr][wv] = a;
      }
      __syncthreads();
      if (tid < 16) r[e * NE + chunk * 16 + tid] = (pr[tid][0] + pr[tid][1]) + (pr[tid][2] + pr[tid][3]);
    }
    grid.sync();
  }
  // final argmax per token: u = 1/(512*r_final); v cancels per token
  {
    int k2 = tid * 2;
    us[k2] = 1.0 / (512.0 * r[e * NE + k2]);
    us[k2 + 1] = 1.0 / (512.0 * r[e * NE + k2 + 1]);
    __syncthreads();
    int col = chunk * 256 + tid;
    const unsigned* cp = bigU + ebase + col;
    double best = -1.0;
    int bi = 0;
#pragma unroll 4
    for (int k = 0; k < NE; ++k) {
      double s = us[k] * fma(-(double)cp[(size_t)k * NTOK], S32, 1.0);
      if (s > best) { best = s; bi = k; }
    }
    idxs[(size_t)e * NTOK + col] = bi;
  }
}

// ---------------- K6: mixture, out0, mse partial, index output ----------------
__global__ __launch_bounds__(256) void k_mix(const float* __restrict__ x, const float* __restrict__ gate,
                                             const float* __restrict__ emb, const int* __restrict__ idxs,
                                             float* __restrict__ xq, float* __restrict__ out0,
                                             float* __restrict__ outIdx, double* __restrict__ mse_sum) {
  int tid = threadIdx.x;
  int sub = tid >> 5, lane = tid & 31;
  int tok = blockIdx.x * 8 + sub;
  float acc[8] = {0, 0, 0, 0, 0, 0, 0, 0};
#pragma unroll
  for (int ee = 0; ee < 10; ++ee) {
    int id = idxs[(size_t)ee * NTOK + tok];
    float g = gate[tok * 10 + ee];
    const float* er = emb + ((size_t)ee * NE + id) * EDIM + lane;
#pragma unroll
    for (int dd = 0; dd < 8; ++dd) acc[dd] = fmaf(g, er[32 * dd], acc[dd]);
  }
  int id10 = idxs[(size_t)10 * NTOK + tok];
  const float* es = emb + ((size_t)10 * NE + id10) * EDIM + lane;
  double ms = 0.0;
#pragma unroll
  for (int dd = 0; dd < 8; ++dd) {
    int d = lane + 32 * dd;
    float q = 0.95f * acc[dd] + 0.05f * es[32 * dd];
    float xv = x[(size_t)tok * EDIM + d];
    float df = q - xv;
    out0[(size_t)tok * EDIM + d] = xv + df;
    xq[(size_t)tok * EDIM + d] = q;
    ms += (double)df * (double)df;
  }
  ms = wredsum(ms);
  __shared__ double pr[4];
  int wv = tid >> 6, ln = tid & 63;
  if (ln == 0) pr[wv] = ms;
  __syncthreads();
  if (tid == 0) atomicAdd(mse_sum, (pr[0] + pr[1]) + (pr[2] + pr[3]));
  if (lane == 0) {
    const float* gr = gate + tok * 10;
    float bg = gr[0];
    int be = 0;
#pragma unroll
    for (int ee = 1; ee < 10; ++ee) { float g = gr[ee]; if (g > bg) { bg = g; be = ee; } }
    outIdx[tok] = (float)idxs[(size_t)be * NTOK + tok];
  }
}

// ---------------- K7: sim = x_q @ emb0^T (f32 GEMM) ----------------
__global__ __launch_bounds__(256) void k_simgemm(const float* __restrict__ xq, const float* __restrict__ emb,
                                                 float* __restrict__ sim) {
  int bx = blockIdx.x, by = blockIdx.y, tid = threadIdx.x;
  int tx = tid & 15, ty = tid >> 4;
  int b0 = bx * 64, j0 = by * 64;
  __shared__ float xs[64][17];
  __shared__ float es[64][17];
  __shared__ float tt[64][68];
  float acc[4][4] = {};
  int lr = tid >> 2, lc = (tid & 3) * 4;
  for (int kc = 0; kc < EDIM; kc += 16) {
    float4 xv = *(const float4*)(xq + (size_t)(b0 + lr) * EDIM + kc + lc);
    float4 ev = *(const float4*)(emb + (size_t)(j0 + lr) * EDIM + kc + lc);
    __syncthreads();
    xs[lr][lc + 0] = xv.x; xs[lr][lc + 1] = xv.y; xs[lr][lc + 2] = xv.z; xs[lr][lc + 3] = xv.w;
    es[lr][lc + 0] = ev.x; es[lr][lc + 1] = ev.y; es[lr][lc + 2] = ev.z; es[lr][lc + 3] = ev.w;
    __syncthreads();
#pragma unroll
    for (int kk = 0; kk < 16; ++kk) {
      float a0 = xs[ty][kk], a1 = xs[ty + 16][kk], a2 = xs[ty + 32][kk], a3 = xs[ty + 48][kk];
      float w0 = es[tx][kk], w1 = es[tx + 16][kk], w2 = es[tx + 32][kk], w3 = es[tx + 48][kk];
      acc[0][0] = fmaf(a0, w0, acc[0][0]); acc[0][1] = fmaf(a0, w1, acc[0][1]);
      acc[0][2] = fmaf(a0, w2, acc[0][2]); acc[0][3] = fmaf(a0, w3, acc[0][3]);
      acc[1][0] = fmaf(a1, w0, acc[1][0]); acc[1][1] = fmaf(a1, w1, acc[1][1]);
      acc[1][2] = fmaf(a1, w2, acc[1][2]); acc[1][3] = fmaf(a1, w3, acc[1][3]);
      acc[2][0] = fmaf(a2, w0, acc[2][0]); acc[2][1] = fmaf(a2, w1, acc[2][1]);
      acc[2][2] = fmaf(a2, w2, acc[2][2]); acc[2][3] = fmaf(a2, w3, acc[2][3]);
      acc[3][0] = fmaf(a3, w0, acc[3][0]); acc[3][1] = fmaf(a3, w1, acc[3][1]);
      acc[3][2] = fmaf(a3, w2, acc[3][2]); acc[3][3] = fmaf(a3, w3, acc[3][3]);
    }
  }
#pragma unroll
  for (int i = 0; i < 4; ++i)
#pragma unroll
    for (int j = 0; j < 4; ++j) tt[ty + 16 * i][tx + 16 * j] = acc[i][j];
  __syncthreads();
  int orow = tid >> 2, oc = (tid & 3) << 4;
  float* ob = sim + (size_t)(b0 + orow) * NE + j0 + oc;
  *(float4*)(ob + 0) = *(float4*)&tt[orow][oc + 0];
  *(float4*)(ob + 4) = *(float4*)&tt[orow][oc + 4];
  *(float4*)(ob + 8) = *(float4*)&tt[orow][oc + 8];
  *(float4*)(ob + 12) = *(float4*)&tt[orow][oc + 12];
}

// ---------------- K8: diversity loss rows ----------------
__global__ __launch_bounds__(256) void k_div(const float* __restrict__ sim, const int* __restrict__ idxs,
                                             const int* __restrict__ label, double* __restrict__ div_sum) {
  __shared__ int lab[NE];
  int tid = threadIdx.x;
  lab[tid] = label[tid];
  lab[256 + tid] = label[256 + tid];
  __syncthreads();
  int wv = tid >> 6, ln = tid & 63;
  int b = blockIdx.x * 4 + wv;
  int ind0 = idxs[b]; // expert 0
  int clu = lab[ind0];
  const float* sr = sim + (size_t)b * NE;
  double vals[8];
  double mx = -1e300;
  int ys = 1024;
#pragma unroll
  for (int c = 0; c < 8; ++c) {
    int j = ln + 64 * c;
    double vv = (double)sr[j];
    if (j == ind0) vv -= 1e12;
    vals[c] = vv;
    mx = fmax(mx, vv);
    if (lab[j] == clu && j != ind0 && j < ys) ys = j;
  }
  for (int o = 32; o > 0; o >>= 1) {
    mx = fmax(mx, __shfl_xor(mx, o, 64));
    ys = min(ys, __shfl_xor(ys, o, 64));
  }
  int y = (ys >= 1024) ? 0 : ys;
  double se = 0.0, vy = 0.0;
#pragma unroll
  for (int c = 0; c < 8; ++c) {
    int j = ln + 64 * c;
    se += exp(vals[c] - mx);
    if (j == y) vy = vals[c];
  }
  for (int o = 32; o > 0; o >>= 1) {
    se += __shfl_xor(se, o, 64);
    vy += __shfl_xor(vy, o, 64);
  }
  if (ln == 0) {
    double lse = mx + log(se);
    atomicAdd(div_sum, lse - vy);
  }
}

// ---------------- K9: loss assembly ----------------
__global__ void k_loss(const double* __restrict__ sums, float* __restrict__ out) {
  double mse = sums[0] / 2097152.0;
  double dv = sums[1] / 8192.0;
  double loss = (mse + 0.25 * mse) + dv;
  out[0] = (float)loss;
}

extern "C" void kernel_launch(void* const* d_in, const int* in_sizes, int n_in,
                              void* d_out, int out_size, void* d_ws, size_t ws_size,
                              hipStream_t stream) {
  (void)in_sizes; (void)n_in; (void)out_size;
  const float* x = (const float*)d_in[0];
  const int* label = (const int*)d_in[1];
  const float* gate = (const float*)d_in[3];
  const float* emb = (const float*)d_in[4];
  float* out = (float*)d_out;
  float* out0 = out;
  float* outLoss = out + (size_t)NTOK * EDIM;
  float* outIdx = out + (size_t)NTOK * EDIM + 1;

  char* w = (char*)d_ws;
  size_t off = 0;
  auto alloc = [&](size_t bytes) -> void* {
    void* p = w + off;
    off += (bytes + 31) & ~(size_t)31;
    return p;
  };
  float* bigF = (float*)alloc((size_t)NEXPALL * NE * NTOK * 4); // d (f32) -> B (u32); later sim
  unsigned* bigU = (unsigned*)bigF;
  float* sim = (float*)bigF;
  unsigned* colminA = (unsigned*)alloc((size_t)NEXPALL * NTOK * 4);
  double* cml = (double*)alloc((size_t)NEXPALL * NTOK * 8);
  double* v = (double*)alloc((size_t)NEXPALL * NTOK * 8);
  double* r = (double*)alloc((size_t)NEXPALL * NE * 8);
  double* uprev = (double*)alloc((size_t)NEXPALL * NE * 8);
  float* sxF = (float*)alloc((size_t)NTOK * 4);
  float* swF = (float*)alloc((size_t)NEXPALL * NE * 4);
  unsigned* dmaxA = (unsigned*)alloc(NEXPALL * 4);
  unsigned* dminA = (unsigned*)alloc(NEXPALL * 4);
  int* ctrl = (int*)alloc(16 * 4); // [0]=nfrozen [1]=snap [2..12]=frozen
  int* idxs = (int*)alloc((size_t)NEXPALL * NTOK * 4);
  float* xq = (float*)alloc((size_t)NTOK * EDIM * 4);
  double* sums = (double*)alloc(2 * 8);
  if (off > ws_size) return; // insufficient workspace

  k_init<<<352, 256, 0, stream>>>(colminA, r, uprev, ctrl, sums, dmaxA, dminA);
  k_npsq<<<NTOK / 16, 256, 0, stream>>>(x, sxF, NTOK);
  k_npsq<<<(NEXPALL * NE) / 16, 256, 0, stream>>>(emb, swF, NEXPALL * NE);
  k_gemm_d<<<dim3(64, 4, NEXPALL), 256, 0, stream>>>(x, emb, sxF, swF, bigF, colminA, dmaxA, dminA);
  k_prep<<<dim3(32, NEXPALL), 256, 0, stream>>>(colminA, dmaxA, dminA, cml, v);
  k_build<<<dim3(4, NE, NEXPALL), 256, 0, stream>>>(bigF, dmaxA, dminA, cml, v, r);

  {
    const unsigned* a0 = bigU;
    double* a1 = r;
    double* a2 = v;
    double* a3 = uprev;
    int* a4 = ctrl + 0;   // nfrozen
    int* a5 = ctrl + 1;   // snap
    int* a6 = ctrl + 2;   // frozen[11]
    int* a7 = idxs;
    void* args[] = {&a0, &a1, &a2, &a3, &a4, &a5, &a6, &a7};
    hipLaunchCooperativeKernel((const void*)k_sink, dim3(NEXPALL * 32), dim3(256), args, 0, stream);
  }

  k_mix<<<NTOK / 8, 256, 0, stream>>>(x, gate, emb, idxs, xq, out0, outIdx, sums);
  k_simgemm<<<dim3(128, 8), 256, 0, stream>>>(xq, emb, sim);
  k_div<<<NTOK / 4, 256, 0, stream>>>(sim, idxs, label, sums + 1);
  k_loss<<<1, 1, 0, stream>>>(sums, outLoss);
}